// Round 10
// baseline (286.389 us; speedup 1.0000x reference)
//
#include <hip/hip_runtime.h>
#include <hip/hip_fp16.h>

typedef __attribute__((ext_vector_type(8))) short short8;
typedef __attribute__((ext_vector_type(4))) short short4v;
typedef __attribute__((ext_vector_type(4))) float floatx4;
typedef _Float16 half8 __attribute__((ext_vector_type(8)));
typedef __fp16 fp16x2 __attribute__((ext_vector_type(2)));
typedef __attribute__((ext_vector_type(4))) unsigned uintx4;

// OCML native exp2: inlines to llvm.amdgcn.exp2 -> v_exp_f32 (compiler-visible).
extern "C" __device__ float __ocml_native_exp2_f32(float);

static __device__ __forceinline__ short f2h(float f) {
    _Float16 h = (_Float16)f;
    return __builtin_bit_cast(short, h);
}

static __device__ __forceinline__ unsigned pkrtz(float a, float b) {
    fp16x2 h = __builtin_amdgcn_cvt_pkrtz(a, b);
    return __builtin_bit_cast(unsigned, h);
}

// Full counter drain before __syncthreads: guarantees prior global_load_lds have
// LANDED in LDS before any wave crosses the barrier (R9-proven race fix).
static __device__ __forceinline__ void drain_all() { __builtin_amdgcn_s_waitcnt(0); }

static __device__ __forceinline__ floatx4 mfma16(short8 a, short8 b, floatx4 c) {
    return __builtin_amdgcn_mfma_f32_16x16x32_f16(__builtin_bit_cast(half8, a),
                                                  __builtin_bit_cast(half8, b), c, 0, 0, 0);
}

static __device__ __forceinline__ void async16(const void* g, void* l) {
    __builtin_amdgcn_global_load_lds((const __attribute__((address_space(1))) void*)g,
                                     (__attribute__((address_space(3))) void*)l, 16, 0, 0);
}

// ---------------------------------------------------------------- LayerNorm -> fp16
__global__ __launch_bounds__(256) void ln_kernel(const float* __restrict__ x,
                                                 const float* __restrict__ gamma,
                                                 const float* __restrict__ beta,
                                                 short* __restrict__ xh) {
    __shared__ float red[8];
    const int row = blockIdx.x, tid = threadIdx.x;
    const int w = tid >> 6, lane = tid & 63;
    const float4 v = ((const float4*)(x + (size_t)row * 1024))[tid];
    float s = v.x + v.y + v.z + v.w;
    float ss = v.x * v.x + v.y * v.y + v.z * v.z + v.w * v.w;
#pragma unroll
    for (int off = 32; off; off >>= 1) {
        s += __shfl_xor(s, off);
        ss += __shfl_xor(ss, off);
    }
    if (lane == 0) { red[w] = s; red[4 + w] = ss; }
    __syncthreads();
    s = red[0] + red[1] + red[2] + red[3];
    ss = red[4] + red[5] + red[6] + red[7];
    const float mu = s * (1.f / 1024.f);
    const float rs = rsqrtf(ss * (1.f / 1024.f) - mu * mu + 1e-5f);
    const float4 g = ((const float4*)gamma)[tid];
    const float4 bt = ((const float4*)beta)[tid];
    short4v ph;
    ph[0] = f2h((v.x - mu) * rs * g.x + bt.x);
    ph[1] = f2h((v.y - mu) * rs * g.y + bt.y);
    ph[2] = f2h((v.z - mu) * rs * g.z + bt.z);
    ph[3] = f2h((v.w - mu) * rs * g.w + bt.w);
    *(short4v*)(xh + (size_t)row * 1024 + tid * 4) = ph;
}

// ------------------------------------------------- transpose + cast fp32 -> fp16
__global__ void tcast_h(const float* __restrict__ in, short* __restrict__ out, int R, int C) {
    __shared__ float t[32][33];
    const int bx = blockIdx.x * 32, by = blockIdx.y * 32;
    const int tx = threadIdx.x, ty = threadIdx.y;
#pragma unroll
    for (int i = 0; i < 32; i += 8) t[ty + i][tx] = in[(size_t)(by + ty + i) * C + bx + tx];
    __syncthreads();
#pragma unroll
    for (int i = 0; i < 32; i += 8) out[(size_t)(bx + ty + i) * R + by + tx] = f2h(t[tx][ty + i]);
}

// ---------------------------------------------------------------- QKV GEMM (plain fp16)
// C = A * BT^T. A: [8192][1024], BT: [3072][1024].
// sA/sB chunk-swizzle: global k-chunk p of row r stored at LDS chunk p ^ ((r>>1)&3)
// (inverse-swizzled SOURCE, linear LDS dest); read at quad ^ ((l15>>1)&3) -> each
// quarter-wave spreads over all 8 bank-slots, 2 lanes each = conflict-free.
// Epilogue: RoPE on q/k; Q scaled by 0.125*log2(e); V transposed -> [bh][d][n] with
// granule half-swap on rows d&8 (consumer attn reads with matching h to kill the
// b64 parity conflicts).
__global__ __launch_bounds__(256, 2) void gemm_qkv(const short* __restrict__ A,
                                                   const short* __restrict__ BT,
                                                   short* __restrict__ Qd, short* __restrict__ Kd,
                                                   short* __restrict__ VTb) {
    extern __shared__ __align__(16) short pool[];  // 34816 B
    short* sA = pool;          // [128][32] (chunk-swizzled)
    short* sB = pool + 4096;   // [128][32] (chunk-swizzled)
    short* sOut = pool;        // alias after barrier: [128][136]

    const int tid = threadIdx.x;
    const int w = tid >> 6, lane = tid & 63, quad = lane >> 4, l15 = lane & 15;
    const int wm = w >> 1, wn = w & 1;
    const int m0 = blockIdx.y * 128, n0 = blockIdx.x * 128;
    const int qsw = (quad ^ ((l15 >> 1) & 3)) * 8;  // swizzled chunk offset (shorts)

    floatx4 acc[4][4];
#pragma unroll
    for (int i = 0; i < 4; i++)
#pragma unroll
        for (int j = 0; j < 4; j++) acc[i][j] = (floatx4){0.f, 0.f, 0.f, 0.f};

    for (int k0 = 0; k0 < 1024; k0 += 32) {
        drain_all();
        __syncthreads();
#pragma unroll
        for (int i = 0; i < 2; ++i) {
            int c = i * 256 + tid;
            int r = c >> 2, kc = ((c & 3) ^ ((r >> 1) & 3)) << 3;  // inverse-swizzled source
            async16(A + (size_t)(m0 + r) * 1024 + k0 + kc, (char*)sA + c * 16);
            async16(BT + (size_t)(n0 + r) * 1024 + k0 + kc, (char*)sB + c * 16);
        }
        drain_all();
        __syncthreads();
        short8 af[4], bf[4];
#pragma unroll
        for (int t = 0; t < 4; t++) {
            af[t] = *(const short8*)(sA + (wm * 64 + t * 16 + l15) * 32 + qsw);
            bf[t] = *(const short8*)(sB + (wn * 64 + t * 16 + l15) * 32 + qsw);
        }
#pragma unroll
        for (int tm = 0; tm < 4; tm++)
#pragma unroll
            for (int tn = 0; tn < 4; tn++) acc[tm][tn] = mfma16(af[tm], bf[tn], acc[tm][tn]);
    }

    drain_all();
    __syncthreads();  // staging reads done; pool becomes sOut

    const int b = m0 >> 11, nnb = m0 & 2047;
    const bool isV = (n0 >= 2048);
    if (!isV) {
        // q scale folds softmax 1/8 and log2(e):  0.125 * 1.4426950408889634
        const float qs = (n0 < 1024) ? 0.18033688011112042f : 1.0f;
#pragma unroll
        for (int tn = 0; tn < 4; tn++) {
            const int d = tn * 16 + l15;
            const int colL = wn * 64 + tn * 16 + l15;
            const float inv = exp2f((float)(d >> 1) * -0.4152410118609203f);
#pragma unroll
            for (int tm = 0; tm < 4; tm++) {
                const int rowL = wm * 64 + tm * 16 + quad * 4;
#pragma unroll
                for (int i = 0; i < 4; i++) {
                    float v = acc[tm][tn][i];
                    float pv = __shfl_xor(v, 1);  // (even,odd) column pair partner
                    float ang = (float)(nnb + rowL + i) * inv;
                    float sn = __sinf(ang), cs = __cosf(ang);
                    float r = (d & 1) ? (pv * sn + v * cs) : (v * cs - pv * sn);
                    sOut[(rowL + i) * 136 + colL] = f2h(r * qs);
                }
            }
        }
        __syncthreads();
        short* dst0 = (n0 < 1024) ? Qd : Kd;
        const int hbase = (n0 & 1023) >> 6;
#pragma unroll
        for (int it = 0; it < 8; ++it) {
            int c = it * 256 + tid;
            int r = c >> 4, cg = (c & 15) * 8;
            int h = hbase + (cg >> 6), d = cg & 63;
            *(short8*)(dst0 + ((size_t)((b * 16 + h) * 2048 + nnb + r)) * 64 + d) =
                *(const short8*)(sOut + r * 136 + cg);
        }
    } else {
#pragma unroll
        for (int tn = 0; tn < 4; tn++) {
            const int colL = wn * 64 + tn * 16 + l15;
#pragma unroll
            for (int tm = 0; tm < 4; tm++) {
                const int rowL = wm * 64 + tm * 16 + quad * 4;
#pragma unroll
                for (int i = 0; i < 4; i++)
                    sOut[colL * 136 + rowL + i] = f2h(acc[tm][tn][i]);  // transposed tile
            }
        }
        __syncthreads();
        const int hbase = (n0 & 1023) >> 6;
#pragma unroll
        for (int it = 0; it < 8; ++it) {
            int c = it * 256 + tid;
            int ci = c >> 4, rg = (c & 15) * 8;
            int h = hbase + (ci >> 6), d = ci & 63;
            short8 v = *(const short8*)(sOut + ci * 136 + rg);
            // granule half-swap for rows d&8: consumer attn reads with
            // h = (G&1)^((d>>3)&1) -> balanced banks on its b64 pairs.
            if (d & 8) v = __builtin_shufflevector(v, v, 4, 5, 6, 7, 0, 1, 2, 3);
            *(short8*)(VTb + ((size_t)((b * 16 + h) * 64 + d)) * 2048 + nnb + rg) = v;
        }
    }
}

// ---------------------------------------------------------------- out-proj GEMM (plain fp16)
__global__ __launch_bounds__(256, 2) void gemm_out(const short* __restrict__ A,
                                                   const short* __restrict__ BT,
                                                   float* __restrict__ Fout,
                                                   const float* __restrict__ bias) {
    __shared__ __align__(16) short sA[128 * 32];
    __shared__ __align__(16) short sB[128 * 32];
    const int tid = threadIdx.x;
    const int w = tid >> 6, lane = tid & 63, quad = lane >> 4, l15 = lane & 15;
    const int wm = w >> 1, wn = w & 1;
    const int m0 = blockIdx.y * 128, n0 = blockIdx.x * 128;
    const int qsw = (quad ^ ((l15 >> 1) & 3)) * 8;

    floatx4 acc[4][4];
#pragma unroll
    for (int i = 0; i < 4; i++)
#pragma unroll
        for (int j = 0; j < 4; j++) acc[i][j] = (floatx4){0.f, 0.f, 0.f, 0.f};

    for (int k0 = 0; k0 < 1024; k0 += 32) {
        drain_all();
        __syncthreads();
#pragma unroll
        for (int i = 0; i < 2; ++i) {
            int c = i * 256 + tid;
            int r = c >> 2, kc = ((c & 3) ^ ((r >> 1) & 3)) << 3;
            async16(A + (size_t)(m0 + r) * 1024 + k0 + kc, (char*)sA + c * 16);
            async16(BT + (size_t)(n0 + r) * 1024 + k0 + kc, (char*)sB + c * 16);
        }
        drain_all();
        __syncthreads();
        short8 af[4], bf[4];
#pragma unroll
        for (int t = 0; t < 4; t++) af[t] = *(const short8*)(sA + (wm * 64 + t * 16 + l15) * 32 + qsw);
#pragma unroll
        for (int t = 0; t < 4; t++) bf[t] = *(const short8*)(sB + (wn * 64 + t * 16 + l15) * 32 + qsw);
#pragma unroll
        for (int tm = 0; tm < 4; tm++)
#pragma unroll
            for (int tn = 0; tn < 4; tn++) acc[tm][tn] = mfma16(af[tm], bf[tn], acc[tm][tn]);
    }

#pragma unroll
    for (int tn = 0; tn < 4; tn++) {
        const int col = n0 + wn * 64 + tn * 16 + l15;
        const float bb = bias[col];
#pragma unroll
        for (int tm = 0; tm < 4; tm++) {
            const int row0 = m0 + wm * 64 + tm * 16 + quad * 4;
#pragma unroll
            for (int i = 0; i < 4; i++) Fout[(size_t)(row0 + i) * 1024 + col] = acc[tm][tn][i] + bb;
        }
    }
}

// ---------------------------------------------------------------- attention (flash, fp16) v9
// R9-passing v8 structure (drain+barrier per tile, native exp2). Changes:
//  * V b64 reads: h = (G&1)^((d>>3)&1) matching the producer's granule half-swap
//    -> quarter-wave covers all 32 banks once; kills the 8.5M parity conflicts.
//  * s_setprio(1) around MFMA clusters (T5; exonerated by R7-without-setprio NaN).
__global__ __launch_bounds__(512, 4) void attn_kernel(const short* __restrict__ Qg,
                                                      const short* __restrict__ Kg,
                                                      const short* __restrict__ VTg,
                                                      short* __restrict__ Og) {
    extern __shared__ __align__(16) short apool[];  // 32768 B
    // per buffer: [0..4095] = K tile [64][64], [4096..8191] = VT tile [64][64]
    short* sKV0 = apool;
    short* sKV1 = apool + 8192;

    const int tid = threadIdx.x;
    const int w = tid >> 6, lane = tid & 63, quad = lane >> 4, l15 = lane & 15;
    const int qt = blockIdx.x, bh = blockIdx.y;

    const short* Qp = Qg + (size_t)(bh * 2048 + qt * 256) * 64;
    const short* Kp = Kg + (size_t)bh * 2048 * 64;
    const short* Vp = VTg + (size_t)bh * 64 * 2048;

    // staging: 512 threads x 16B = one 8KB tile each for K and VT.
    // LDS dest linear; source chunk inverse-swizzled: c_log = c_phys ^ (row&7).
    const int str = tid >> 3, stc = tid & 7;
    const int scl = stc ^ (str & 7);
    const int kSrcOff = str * 64 + scl * 8;    // shorts; + n0*64
    const int vSrcOff = str * 2048 + scl * 8;  // shorts; + n0
    const int dstOff = tid * 16;               // bytes within tile half

    short8 aq[2][2];
#pragma unroll
    for (int rb = 0; rb < 2; rb++)
#pragma unroll
        for (int kh = 0; kh < 2; kh++)
            aq[rb][kh] = *(const short8*)(Qp + (w * 32 + rb * 16 + l15) * 64 + kh * 32 + quad * 8);

    short8 ones;
#pragma unroll
    for (int j = 0; j < 8; j++) ones[j] = 0x3C00;  // 1.0h

    floatx4 o4[2][4], ol[2];
#pragma unroll
    for (int rb = 0; rb < 2; rb++) {
#pragma unroll
        for (int dt = 0; dt < 4; dt++) o4[rb][dt] = (floatx4){0.f, 0.f, 0.f, 0.f};
        ol[rb] = (floatx4){0.f, 0.f, 0.f, 0.f};
    }

    // prologue: stage tile 0 into buffer 0
    async16(Kp + kSrcOff, (char*)sKV0 + dstOff);
    async16(Vp + vSrcOff, (char*)(sKV0 + 4096) + dstOff);

    const int swz0 = (quad ^ (l15 & 7)) << 3;        // K d-chunk quad   (d 0..31)
    const int swz1 = ((4 | quad) ^ (l15 & 7)) << 3;  // K d-chunk 4|quad (d 32..63)

    for (int kt = 0; kt < 32; ++kt) {
        const short* sK = (kt & 1) ? sKV1 : sKV0;
        const short* sVT = sK + 4096;
        drain_all();      // staged loads for buf[cur] have LANDED in LDS
        __syncthreads();  // ... before any wave proceeds to read buf[cur]
        if (kt + 1 < 32) {
            short* nK = (kt & 1) ? sKV0 : sKV1;
            const int n0 = (kt + 1) * 64;
            async16(Kp + (size_t)n0 * 64 + kSrcOff, (char*)nK + dstOff);
            async16(Vp + n0 + vSrcOff, (char*)(nK + 4096) + dstOff);
        }

#pragma unroll
        for (int nc = 0; nc < 2; nc++) {
            // ---- QK^T (swapped: A=K rows -> kv, B=Q -> q cols) for tn = 2nc, 2nc+1
            floatx4 zA[2], zB[2];
            {
                const int rbase = ((2 * nc) * 16 + l15) * 64;
                short8 k0 = *(const short8*)(sK + rbase + swz0);
                short8 k1 = *(const short8*)(sK + rbase + swz1);
                __builtin_amdgcn_s_setprio(1);
#pragma unroll
                for (int rb = 0; rb < 2; rb++) {
                    floatx4 z = (floatx4){0.f, 0.f, 0.f, 0.f};
                    z = mfma16(k0, aq[rb][0], z);
                    z = mfma16(k1, aq[rb][1], z);
                    zA[rb] = z;
                }
                __builtin_amdgcn_s_setprio(0);
            }
            {
                const int rbase = ((2 * nc + 1) * 16 + l15) * 64;
                short8 k0 = *(const short8*)(sK + rbase + swz0);
                short8 k1 = *(const short8*)(sK + rbase + swz1);
                __builtin_amdgcn_s_setprio(1);
#pragma unroll
                for (int rb = 0; rb < 2; rb++) {
                    floatx4 z = (floatx4){0.f, 0.f, 0.f, 0.f};
                    z = mfma16(k0, aq[rb][0], z);
                    z = mfma16(k1, aq[rb][1], z);
                    zB[rb] = z;
                }
                __builtin_amdgcn_s_setprio(0);
            }

            // ---- VT A-fragments matching the relabeled k-slots:
            // element j of lane (quad,l15) = VT[d=dt*16+l15][nc*32 + 16*(j>>2) + 4*quad + (j&3)]
            // granule G = nc*8 + 4*(j>>2) + quad; chunk = (G>>1)^(d&7);
            // half = (G&1)^((d>>3)&1)  [producer swapped granule halves on d&8 rows].
            short8 pa[4];
            const int r7 = l15 & 7;
            const int h4 = ((quad ^ (l15 >> 3)) & 1) << 2;
            const int cLo = (((nc << 2) | (quad >> 1)) ^ r7) << 3;
            const int cHi = ((((nc << 2) + 2) | (quad >> 1)) ^ r7) << 3;
#pragma unroll
            for (int dt = 0; dt < 4; dt++) {
                const short* rowp = sVT + (dt * 16 + l15) * 64;
                short4v lo = *(const short4v*)(rowp + cLo + h4);
                short4v hi = *(const short4v*)(rowp + cHi + h4);
                pa[dt] = __builtin_shufflevector(lo, hi, 0, 1, 2, 3, 4, 5, 6, 7);
            }

            // ---- p = exp2(z) (native), pack rtz -> pb (no lane moves); PV MFMA
#pragma unroll
            for (int rb = 0; rb < 2; rb++) {
                uintx4 pbw;
                pbw.x = pkrtz(__ocml_native_exp2_f32(zA[rb][0]),
                              __ocml_native_exp2_f32(zA[rb][1]));  // kv = 4q+0,1
                pbw.y = pkrtz(__ocml_native_exp2_f32(zA[rb][2]),
                              __ocml_native_exp2_f32(zA[rb][3]));  // kv = 4q+2,3
                pbw.z = pkrtz(__ocml_native_exp2_f32(zB[rb][0]),
                              __ocml_native_exp2_f32(zB[rb][1]));  // kv = 16+4q+0,1
                pbw.w = pkrtz(__ocml_native_exp2_f32(zB[rb][2]),
                              __ocml_native_exp2_f32(zB[rb][3]));  // kv = 16+4q+2,3
                short8 pb = __builtin_bit_cast(short8, pbw);
                __builtin_amdgcn_s_setprio(1);
#pragma unroll
                for (int dt = 0; dt < 4; dt++) o4[rb][dt] = mfma16(pa[dt], pb, o4[rb][dt]);
                ol[rb] = mfma16(ones, pb, ol[rb]);
                __builtin_amdgcn_s_setprio(0);
            }
        }
    }

    float linv[2];
    linv[0] = 1.0f / ol[0][0];  // l[q = w*32 + l15]; all 4 acc rows equal
    linv[1] = 1.0f / ol[1][0];

    drain_all();
    __syncthreads();  // last tile reads done; reuse apool as out-stage [256][64] (swizzled)
    short* sO = apool;
#pragma unroll
    for (int rb = 0; rb < 2; rb++) {
        const int q = w * 32 + rb * 16 + l15;
#pragma unroll
        for (int dt = 0; dt < 4; dt++) {
            short4v pk;
#pragma unroll
            for (int i = 0; i < 4; i++) pk[i] = f2h(o4[rb][dt][i] * linv[rb]);
            const int d0 = dt * 16 + quad * 4;
            *(short4v*)(sO + q * 64 + (((d0 >> 3) ^ (q & 7)) << 3) + (d0 & 7)) = pk;
        }
    }
    drain_all();
    __syncthreads();
    const int b = bh >> 4, h = bh & 15;
#pragma unroll
    for (int it = 0; it < 4; ++it) {
        int g = it * 512 + tid;
        int r = g >> 3, c = g & 7;
        *(short8*)(Og + (size_t)(b * 2048 + qt * 256 + r) * 1024 + h * 64 + c * 8) =
            *(const short8*)(sO + r * 64 + ((c ^ (r & 7)) << 3));
    }
}

// ---------------------------------------------------------------- launch
extern "C" void kernel_launch(void* const* d_in, const int* in_sizes, int n_in, void* d_out,
                              int out_size, void* d_ws, size_t ws_size, hipStream_t stream) {
    const float* x = (const float*)d_in[0];
    const float* gamma = (const float*)d_in[1];
    const float* beta = (const float*)d_in[2];
    const float* w_qkv = (const float*)d_in[3];
    const float* w_out = (const float*)d_in[4];
    const float* b_out = (const float*)d_in[5];
    float* out = (float*)d_out;

    char* ws = (char*)d_ws;
    short* xh = (short*)ws;                   // [8192][1024] fp16; later reused as attn out
    short* wqkvT = (short*)(ws + 16777216);   // [3072][1024]
    short* woT = (short*)(ws + 23068672);     // [1024][1024]
    short* VTb = (short*)(ws + 25165824);     // [64][64][2048] (granule half-swap on d&8)
    // Q and K live in d_out (2 x 16.78 MB); final GEMM overwrites it.
    short* Qd = (short*)d_out;                // [64][2048][64] (roped, scaled)
    short* Kd = (short*)d_out + 8388608;      // [64][2048][64] (roped)

    ln_kernel<<<8192, 256, 0, stream>>>(x, gamma, beta, xh);
    tcast_h<<<dim3(96, 32), dim3(32, 8), 0, stream>>>(w_qkv, wqkvT, 1024, 3072);
    tcast_h<<<dim3(32, 32), dim3(32, 8), 0, stream>>>(w_out, woT, 1024, 1024);
    gemm_qkv<<<dim3(24, 64), 256, 34816, stream>>>(xh, wqkvT, Qd, Kd, VTb);
    attn_kernel<<<dim3(8, 64), 512, 32768, stream>>>(Qd, Kd, VTb, xh);
    gemm_out<<<dim3(8, 64), 256, 0, stream>>>(xh, woT, out, b_out);
}

// Round 11
// 266.265 us; speedup vs baseline: 1.0756x; 1.0756x over previous
//
#include <hip/hip_runtime.h>
#include <hip/hip_fp16.h>

typedef __attribute__((ext_vector_type(8))) short short8;
typedef __attribute__((ext_vector_type(4))) short short4v;
typedef __attribute__((ext_vector_type(4))) float floatx4;
typedef _Float16 half8 __attribute__((ext_vector_type(8)));
typedef __fp16 fp16x2 __attribute__((ext_vector_type(2)));
typedef __attribute__((ext_vector_type(4))) unsigned uintx4;

// OCML native exp2: inlines to llvm.amdgcn.exp2 -> v_exp_f32 (compiler-visible).
extern "C" __device__ float __ocml_native_exp2_f32(float);

static __device__ __forceinline__ short f2h(float f) {
    _Float16 h = (_Float16)f;
    return __builtin_bit_cast(short, h);
}

static __device__ __forceinline__ unsigned pkrtz(float a, float b) {
    fp16x2 h = __builtin_amdgcn_cvt_pkrtz(a, b);
    return __builtin_bit_cast(unsigned, h);
}

// Full counter drain before __syncthreads: guarantees prior global_load_lds have
// LANDED in LDS before any wave crosses the barrier (R9-proven race fix).
static __device__ __forceinline__ void drain_all() { __builtin_amdgcn_s_waitcnt(0); }

static __device__ __forceinline__ floatx4 mfma16(short8 a, short8 b, floatx4 c) {
    return __builtin_amdgcn_mfma_f32_16x16x32_f16(__builtin_bit_cast(half8, a),
                                                  __builtin_bit_cast(half8, b), c, 0, 0, 0);
}

static __device__ __forceinline__ void async16(const void* g, void* l) {
    __builtin_amdgcn_global_load_lds((const __attribute__((address_space(1))) void*)g,
                                     (__attribute__((address_space(3))) void*)l, 16, 0, 0);
}

// ---------------------------------------------------------------- LayerNorm -> fp16
__global__ __launch_bounds__(256) void ln_kernel(const float* __restrict__ x,
                                                 const float* __restrict__ gamma,
                                                 const float* __restrict__ beta,
                                                 short* __restrict__ xh) {
    __shared__ float red[8];
    const int row = blockIdx.x, tid = threadIdx.x;
    const int w = tid >> 6, lane = tid & 63;
    const float4 v = ((const float4*)(x + (size_t)row * 1024))[tid];
    float s = v.x + v.y + v.z + v.w;
    float ss = v.x * v.x + v.y * v.y + v.z * v.z + v.w * v.w;
#pragma unroll
    for (int off = 32; off; off >>= 1) {
        s += __shfl_xor(s, off);
        ss += __shfl_xor(ss, off);
    }
    if (lane == 0) { red[w] = s; red[4 + w] = ss; }
    __syncthreads();
    s = red[0] + red[1] + red[2] + red[3];
    ss = red[4] + red[5] + red[6] + red[7];
    const float mu = s * (1.f / 1024.f);
    const float rs = rsqrtf(ss * (1.f / 1024.f) - mu * mu + 1e-5f);
    const float4 g = ((const float4*)gamma)[tid];
    const float4 bt = ((const float4*)beta)[tid];
    short4v ph;
    ph[0] = f2h((v.x - mu) * rs * g.x + bt.x);
    ph[1] = f2h((v.y - mu) * rs * g.y + bt.y);
    ph[2] = f2h((v.z - mu) * rs * g.z + bt.z);
    ph[3] = f2h((v.w - mu) * rs * g.w + bt.w);
    *(short4v*)(xh + (size_t)row * 1024 + tid * 4) = ph;
}

// ------------------------------------------------- transpose + cast fp32 -> fp16
__global__ void tcast_h(const float* __restrict__ in, short* __restrict__ out, int R, int C) {
    __shared__ float t[32][33];
    const int bx = blockIdx.x * 32, by = blockIdx.y * 32;
    const int tx = threadIdx.x, ty = threadIdx.y;
#pragma unroll
    for (int i = 0; i < 32; i += 8) t[ty + i][tx] = in[(size_t)(by + ty + i) * C + bx + tx];
    __syncthreads();
#pragma unroll
    for (int i = 0; i < 32; i += 8) out[(size_t)(bx + ty + i) * R + by + tx] = f2h(t[tx][ty + i]);
}

// ---------------------------------------------------------------- QKV GEMM (plain fp16)
// C = A * BT^T. A: [8192][1024], BT: [3072][1024].
// v2 K-loop: double-buffered LDS (2 x {sA,sB} = 32KB), stage-next issued DURING
// compute-current, ONE drain+barrier per K-step (attn-proven 2-phase schedule).
// sA/sB chunk-swizzle (R10): k-chunk p of row r at LDS chunk p ^ ((r>>1)&3);
// read at quad ^ ((l15>>1)&3) -> conflict-free fragment reads.
// Epilogue: RoPE on q/k; Q scaled by 0.125*log2(e); V transposed -> [bh][d][n] with
// granule half-swap on rows d&8 (consumer attn reads matching half).
__global__ __launch_bounds__(256, 4) void gemm_qkv(const short* __restrict__ A,
                                                   const short* __restrict__ BT,
                                                   short* __restrict__ Qd, short* __restrict__ Kd,
                                                   short* __restrict__ VTb) {
    extern __shared__ __align__(16) short pool[];  // 34816 B
    // buf0: pool[0..8191] = {sA0[4096], sB0[4096]}; buf1: pool[8192..16383]
    short* sOut = pool;  // alias after the K-loop's final barrier: [128][136]

    const int tid = threadIdx.x;
    const int w = tid >> 6, lane = tid & 63, quad = lane >> 4, l15 = lane & 15;
    const int wm = w >> 1, wn = w & 1;
    const int m0 = blockIdx.y * 128, n0 = blockIdx.x * 128;
    const int qsw = (quad ^ ((l15 >> 1) & 3)) * 8;  // swizzled chunk offset (shorts)

    // staging thread constants
    int sr[2], skc[2];
#pragma unroll
    for (int i = 0; i < 2; ++i) {
        int c = i * 256 + tid;
        sr[i] = c >> 2;
        skc[i] = ((c & 3) ^ ((sr[i] >> 1) & 3)) << 3;  // inverse-swizzled source chunk
    }

    floatx4 acc[4][4];
#pragma unroll
    for (int i = 0; i < 4; i++)
#pragma unroll
        for (int j = 0; j < 4; j++) acc[i][j] = (floatx4){0.f, 0.f, 0.f, 0.f};

    // prologue: stage K-tile 0 into buf0
#pragma unroll
    for (int i = 0; i < 2; ++i) {
        int c = i * 256 + tid;
        async16(A + (size_t)(m0 + sr[i]) * 1024 + skc[i], (char*)pool + c * 16);
        async16(BT + (size_t)(n0 + sr[i]) * 1024 + skc[i], (char*)(pool + 4096) + c * 16);
    }
    drain_all();
    __syncthreads();

    for (int kt = 0; kt < 32; ++kt) {
        const short* cA = pool + (kt & 1) * 8192;
        const short* cB = cA + 4096;
        if (kt + 1 < 32) {  // issue next-tile stage into the idle buffer
            short* nA = pool + ((kt + 1) & 1) * 8192;
            const int k0 = (kt + 1) * 32;
#pragma unroll
            for (int i = 0; i < 2; ++i) {
                int c = i * 256 + tid;
                async16(A + (size_t)(m0 + sr[i]) * 1024 + k0 + skc[i], (char*)nA + c * 16);
                async16(BT + (size_t)(n0 + sr[i]) * 1024 + k0 + skc[i], (char*)(nA + 4096) + c * 16);
            }
        }
        short8 af[4], bf[4];
#pragma unroll
        for (int t = 0; t < 4; t++) {
            af[t] = *(const short8*)(cA + (wm * 64 + t * 16 + l15) * 32 + qsw);
            bf[t] = *(const short8*)(cB + (wn * 64 + t * 16 + l15) * 32 + qsw);
        }
#pragma unroll
        for (int tm = 0; tm < 4; tm++)
#pragma unroll
            for (int tn = 0; tn < 4; tn++) acc[tm][tn] = mfma16(af[tm], bf[tn], acc[tm][tn]);
        drain_all();      // next-tile loads LANDED; our ds_reads complete
        __syncthreads();  // safe to overwrite the buffer read last iteration
    }

    // (loop ends with drain+barrier: pool is free; becomes sOut)
    const int b = m0 >> 11, nnb = m0 & 2047;
    const bool isV = (n0 >= 2048);
    if (!isV) {
        // q scale folds softmax 1/8 and log2(e):  0.125 * 1.4426950408889634
        const float qs = (n0 < 1024) ? 0.18033688011112042f : 1.0f;
#pragma unroll
        for (int tn = 0; tn < 4; tn++) {
            const int d = tn * 16 + l15;
            const int colL = wn * 64 + tn * 16 + l15;
            const float inv = exp2f((float)(d >> 1) * -0.4152410118609203f);
#pragma unroll
            for (int tm = 0; tm < 4; tm++) {
                const int rowL = wm * 64 + tm * 16 + quad * 4;
#pragma unroll
                for (int i = 0; i < 4; i++) {
                    float v = acc[tm][tn][i];
                    float pv = __shfl_xor(v, 1);  // (even,odd) column pair partner
                    float ang = (float)(nnb + rowL + i) * inv;
                    float sn = __sinf(ang), cs = __cosf(ang);
                    float r = (d & 1) ? (pv * sn + v * cs) : (v * cs - pv * sn);
                    sOut[(rowL + i) * 136 + colL] = f2h(r * qs);
                }
            }
        }
        __syncthreads();
        short* dst0 = (n0 < 1024) ? Qd : Kd;
        const int hbase = (n0 & 1023) >> 6;
#pragma unroll
        for (int it = 0; it < 8; ++it) {
            int c = it * 256 + tid;
            int r = c >> 4, cg = (c & 15) * 8;
            int h = hbase + (cg >> 6), d = cg & 63;
            *(short8*)(dst0 + ((size_t)((b * 16 + h) * 2048 + nnb + r)) * 64 + d) =
                *(const short8*)(sOut + r * 136 + cg);
        }
    } else {
#pragma unroll
        for (int tn = 0; tn < 4; tn++) {
            const int colL = wn * 64 + tn * 16 + l15;
#pragma unroll
            for (int tm = 0; tm < 4; tm++) {
                const int rowL = wm * 64 + tm * 16 + quad * 4;
#pragma unroll
                for (int i = 0; i < 4; i++)
                    sOut[colL * 136 + rowL + i] = f2h(acc[tm][tn][i]);  // transposed tile
            }
        }
        __syncthreads();
        const int hbase = (n0 & 1023) >> 6;
#pragma unroll
        for (int it = 0; it < 8; ++it) {
            int c = it * 256 + tid;
            int ci = c >> 4, rg = (c & 15) * 8;
            int h = hbase + (ci >> 6), d = ci & 63;
            short8 v = *(const short8*)(sOut + ci * 136 + rg);
            // granule half-swap for rows d&8: consumer attn reads with
            // h = (G&1)^((d>>3)&1) -> balanced banks on its b64 pairs.
            if (d & 8) v = __builtin_shufflevector(v, v, 4, 5, 6, 7, 0, 1, 2, 3);
            *(short8*)(VTb + ((size_t)((b * 16 + h) * 64 + d)) * 2048 + nnb + rg) = v;
        }
    }
}

// ---------------------------------------------------------------- out-proj GEMM (plain fp16)
// Same 2-phase double-buffered K-loop as gemm_qkv.
__global__ __launch_bounds__(256, 4) void gemm_out(const short* __restrict__ A,
                                                   const short* __restrict__ BT,
                                                   float* __restrict__ Fout,
                                                   const float* __restrict__ bias) {
    __shared__ __align__(16) short pool2[16384];  // 2 x {sA,sB} = 32KB
    const int tid = threadIdx.x;
    const int w = tid >> 6, lane = tid & 63, quad = lane >> 4, l15 = lane & 15;
    const int wm = w >> 1, wn = w & 1;
    const int m0 = blockIdx.y * 128, n0 = blockIdx.x * 128;
    const int qsw = (quad ^ ((l15 >> 1) & 3)) * 8;

    int sr[2], skc[2];
#pragma unroll
    for (int i = 0; i < 2; ++i) {
        int c = i * 256 + tid;
        sr[i] = c >> 2;
        skc[i] = ((c & 3) ^ ((sr[i] >> 1) & 3)) << 3;
    }

    floatx4 acc[4][4];
#pragma unroll
    for (int i = 0; i < 4; i++)
#pragma unroll
        for (int j = 0; j < 4; j++) acc[i][j] = (floatx4){0.f, 0.f, 0.f, 0.f};

#pragma unroll
    for (int i = 0; i < 2; ++i) {
        int c = i * 256 + tid;
        async16(A + (size_t)(m0 + sr[i]) * 1024 + skc[i], (char*)pool2 + c * 16);
        async16(BT + (size_t)(n0 + sr[i]) * 1024 + skc[i], (char*)(pool2 + 4096) + c * 16);
    }
    drain_all();
    __syncthreads();

    for (int kt = 0; kt < 32; ++kt) {
        const short* cA = pool2 + (kt & 1) * 8192;
        const short* cB = cA + 4096;
        if (kt + 1 < 32) {
            short* nA = pool2 + ((kt + 1) & 1) * 8192;
            const int k0 = (kt + 1) * 32;
#pragma unroll
            for (int i = 0; i < 2; ++i) {
                int c = i * 256 + tid;
                async16(A + (size_t)(m0 + sr[i]) * 1024 + k0 + skc[i], (char*)nA + c * 16);
                async16(BT + (size_t)(n0 + sr[i]) * 1024 + k0 + skc[i], (char*)(nA + 4096) + c * 16);
            }
        }
        short8 af[4], bf[4];
#pragma unroll
        for (int t = 0; t < 4; t++) af[t] = *(const short8*)(cA + (wm * 64 + t * 16 + l15) * 32 + qsw);
#pragma unroll
        for (int t = 0; t < 4; t++) bf[t] = *(const short8*)(cB + (wn * 64 + t * 16 + l15) * 32 + qsw);
#pragma unroll
        for (int tm = 0; tm < 4; tm++)
#pragma unroll
            for (int tn = 0; tn < 4; tn++) acc[tm][tn] = mfma16(af[tm], bf[tn], acc[tm][tn]);
        drain_all();
        __syncthreads();
    }

#pragma unroll
    for (int tn = 0; tn < 4; tn++) {
        const int col = n0 + wn * 64 + tn * 16 + l15;
        const float bb = bias[col];
#pragma unroll
        for (int tm = 0; tm < 4; tm++) {
            const int row0 = m0 + wm * 64 + tm * 16 + quad * 4;
#pragma unroll
            for (int i = 0; i < 4; i++) Fout[(size_t)(row0 + i) * 1024 + col] = acc[tm][tn][i] + bb;
        }
    }
}

// ---------------------------------------------------------------- attention (flash, fp16) v9
// Byte-identical to R10 (passed): drain+barrier per tile, native exp2, V half-swap
// read (h = (G&1)^((d>>3)&1)), setprio around MFMA clusters.
__global__ __launch_bounds__(512, 4) void attn_kernel(const short* __restrict__ Qg,
                                                      const short* __restrict__ Kg,
                                                      const short* __restrict__ VTg,
                                                      short* __restrict__ Og) {
    extern __shared__ __align__(16) short apool[];  // 32768 B
    // per buffer: [0..4095] = K tile [64][64], [4096..8191] = VT tile [64][64]
    short* sKV0 = apool;
    short* sKV1 = apool + 8192;

    const int tid = threadIdx.x;
    const int w = tid >> 6, lane = tid & 63, quad = lane >> 4, l15 = lane & 15;
    const int qt = blockIdx.x, bh = blockIdx.y;

    const short* Qp = Qg + (size_t)(bh * 2048 + qt * 256) * 64;
    const short* Kp = Kg + (size_t)bh * 2048 * 64;
    const short* Vp = VTg + (size_t)bh * 64 * 2048;

    // staging: 512 threads x 16B = one 8KB tile each for K and VT.
    // LDS dest linear; source chunk inverse-swizzled: c_log = c_phys ^ (row&7).
    const int str = tid >> 3, stc = tid & 7;
    const int scl = stc ^ (str & 7);
    const int kSrcOff = str * 64 + scl * 8;    // shorts; + n0*64
    const int vSrcOff = str * 2048 + scl * 8;  // shorts; + n0
    const int dstOff = tid * 16;               // bytes within tile half

    short8 aq[2][2];
#pragma unroll
    for (int rb = 0; rb < 2; rb++)
#pragma unroll
        for (int kh = 0; kh < 2; kh++)
            aq[rb][kh] = *(const short8*)(Qp + (w * 32 + rb * 16 + l15) * 64 + kh * 32 + quad * 8);

    short8 ones;
#pragma unroll
    for (int j = 0; j < 8; j++) ones[j] = 0x3C00;  // 1.0h

    floatx4 o4[2][4], ol[2];
#pragma unroll
    for (int rb = 0; rb < 2; rb++) {
#pragma unroll
        for (int dt = 0; dt < 4; dt++) o4[rb][dt] = (floatx4){0.f, 0.f, 0.f, 0.f};
        ol[rb] = (floatx4){0.f, 0.f, 0.f, 0.f};
    }

    // prologue: stage tile 0 into buffer 0
    async16(Kp + kSrcOff, (char*)sKV0 + dstOff);
    async16(Vp + vSrcOff, (char*)(sKV0 + 4096) + dstOff);

    const int swz0 = (quad ^ (l15 & 7)) << 3;        // K d-chunk quad   (d 0..31)
    const int swz1 = ((4 | quad) ^ (l15 & 7)) << 3;  // K d-chunk 4|quad (d 32..63)

    for (int kt = 0; kt < 32; ++kt) {
        const short* sK = (kt & 1) ? sKV1 : sKV0;
        const short* sVT = sK + 4096;
        drain_all();      // staged loads for buf[cur] have LANDED in LDS
        __syncthreads();  // ... before any wave proceeds to read buf[cur]
        if (kt + 1 < 32) {
            short* nK = (kt & 1) ? sKV0 : sKV1;
            const int n0 = (kt + 1) * 64;
            async16(Kp + (size_t)n0 * 64 + kSrcOff, (char*)nK + dstOff);
            async16(Vp + n0 + vSrcOff, (char*)(nK + 4096) + dstOff);
        }

#pragma unroll
        for (int nc = 0; nc < 2; nc++) {
            // ---- QK^T (swapped: A=K rows -> kv, B=Q -> q cols) for tn = 2nc, 2nc+1
            floatx4 zA[2], zB[2];
            {
                const int rbase = ((2 * nc) * 16 + l15) * 64;
                short8 k0 = *(const short8*)(sK + rbase + swz0);
                short8 k1 = *(const short8*)(sK + rbase + swz1);
                __builtin_amdgcn_s_setprio(1);
#pragma unroll
                for (int rb = 0; rb < 2; rb++) {
                    floatx4 z = (floatx4){0.f, 0.f, 0.f, 0.f};
                    z = mfma16(k0, aq[rb][0], z);
                    z = mfma16(k1, aq[rb][1], z);
                    zA[rb] = z;
                }
                __builtin_amdgcn_s_setprio(0);
            }
            {
                const int rbase = ((2 * nc + 1) * 16 + l15) * 64;
                short8 k0 = *(const short8*)(sK + rbase + swz0);
                short8 k1 = *(const short8*)(sK + rbase + swz1);
                __builtin_amdgcn_s_setprio(1);
#pragma unroll
                for (int rb = 0; rb < 2; rb++) {
                    floatx4 z = (floatx4){0.f, 0.f, 0.f, 0.f};
                    z = mfma16(k0, aq[rb][0], z);
                    z = mfma16(k1, aq[rb][1], z);
                    zB[rb] = z;
                }
                __builtin_amdgcn_s_setprio(0);
            }

            // ---- VT A-fragments matching the relabeled k-slots:
            // element j of lane (quad,l15) = VT[d=dt*16+l15][nc*32 + 16*(j>>2) + 4*quad + (j&3)]
            // granule G = nc*8 + 4*(j>>2) + quad; chunk = (G>>1)^(d&7);
            // half = (G&1)^((d>>3)&1)  [producer swapped granule halves on d&8 rows].
            short8 pa[4];
            const int r7 = l15 & 7;
            const int h4 = ((quad ^ (l15 >> 3)) & 1) << 2;
            const int cLo = (((nc << 2) | (quad >> 1)) ^ r7) << 3;
            const int cHi = ((((nc << 2) + 2) | (quad >> 1)) ^ r7) << 3;
#pragma unroll
            for (int dt = 0; dt < 4; dt++) {
                const short* rowp = sVT + (dt * 16 + l15) * 64;
                short4v lo = *(const short4v*)(rowp + cLo + h4);
                short4v hi = *(const short4v*)(rowp + cHi + h4);
                pa[dt] = __builtin_shufflevector(lo, hi, 0, 1, 2, 3, 4, 5, 6, 7);
            }

            // ---- p = exp2(z) (native), pack rtz -> pb (no lane moves); PV MFMA
#pragma unroll
            for (int rb = 0; rb < 2; rb++) {
                uintx4 pbw;
                pbw.x = pkrtz(__ocml_native_exp2_f32(zA[rb][0]),
                              __ocml_native_exp2_f32(zA[rb][1]));  // kv = 4q+0,1
                pbw.y = pkrtz(__ocml_native_exp2_f32(zA[rb][2]),
                              __ocml_native_exp2_f32(zA[rb][3]));  // kv = 4q+2,3
                pbw.z = pkrtz(__ocml_native_exp2_f32(zB[rb][0]),
                              __ocml_native_exp2_f32(zB[rb][1]));  // kv = 16+4q+0,1
                pbw.w = pkrtz(__ocml_native_exp2_f32(zB[rb][2]),
                              __ocml_native_exp2_f32(zB[rb][3]));  // kv = 16+4q+2,3
                short8 pb = __builtin_bit_cast(short8, pbw);
                __builtin_amdgcn_s_setprio(1);
#pragma unroll
                for (int dt = 0; dt < 4; dt++) o4[rb][dt] = mfma16(pa[dt], pb, o4[rb][dt]);
                ol[rb] = mfma16(ones, pb, ol[rb]);
                __builtin_amdgcn_s_setprio(0);
            }
        }
    }

    float linv[2];
    linv[0] = 1.0f / ol[0][0];  // l[q = w*32 + l15]; all 4 acc rows equal
    linv[1] = 1.0f / ol[1][0];

    drain_all();
    __syncthreads();  // last tile reads done; reuse apool as out-stage [256][64] (swizzled)
    short* sO = apool;
#pragma unroll
    for (int rb = 0; rb < 2; rb++) {
        const int q = w * 32 + rb * 16 + l15;
#pragma unroll
        for (int dt = 0; dt < 4; dt++) {
            short4v pk;
#pragma unroll
            for (int i = 0; i < 4; i++) pk[i] = f2h(o4[rb][dt][i] * linv[rb]);
            const int d0 = dt * 16 + quad * 4;
            *(short4v*)(sO + q * 64 + (((d0 >> 3) ^ (q & 7)) << 3) + (d0 & 7)) = pk;
        }
    }
    drain_all();
    __syncthreads();
    const int b = bh >> 4, h = bh & 15;
#pragma unroll
    for (int it = 0; it < 4; ++it) {
        int g = it * 512 + tid;
        int r = g >> 3, c = g & 7;
        *(short8*)(Og + (size_t)(b * 2048 + qt * 256 + r) * 1024 + h * 64 + c * 8) =
            *(const short8*)(sO + r * 64 + ((c ^ (r & 7)) << 3));
    }
}

// ---------------------------------------------------------------- launch
extern "C" void kernel_launch(void* const* d_in, const int* in_sizes, int n_in, void* d_out,
                              int out_size, void* d_ws, size_t ws_size, hipStream_t stream) {
    const float* x = (const float*)d_in[0];
    const float* gamma = (const float*)d_in[1];
    const float* beta = (const float*)d_in[2];
    const float* w_qkv = (const float*)d_in[3];
    const float* w_out = (const float*)d_in[4];
    const float* b_out = (const float*)d_in[5];
    float* out = (float*)d_out;

    char* ws = (char*)d_ws;
    short* xh = (short*)ws;                   // [8192][1024] fp16; later reused as attn out
    short* wqkvT = (short*)(ws + 16777216);   // [3072][1024]
    short* woT = (short*)(ws + 23068672);     // [1024][1024]
    short* VTb = (short*)(ws + 25165824);     // [64][64][2048] (granule half-swap on d&8)
    // Q and K live in d_out (2 x 16.78 MB); final GEMM overwrites it.
    short* Qd = (short*)d_out;                // [64][2048][64] (roped, scaled)
    short* Kd = (short*)d_out + 8388608;      // [64][2048][64] (roped)

    ln_kernel<<<8192, 256, 0, stream>>>(x, gamma, beta, xh);
    tcast_h<<<dim3(96, 32), dim3(32, 8), 0, stream>>>(w_qkv, wqkvT, 1024, 3072);
    tcast_h<<<dim3(32, 32), dim3(32, 8), 0, stream>>>(w_out, woT, 1024, 1024);
    gemm_qkv<<<dim3(24, 64), 256, 34816, stream>>>(xh, wqkvT, Qd, Kd, VTb);
    attn_kernel<<<dim3(8, 64), 512, 32768, stream>>>(Qd, Kd, VTb, xh);
    gemm_out<<<dim3(8, 64), 256, 0, stream>>>(xh, woT, out, b_out);
}